// Round 2
// baseline (366.542 us; speedup 1.0000x reference)
//
#include <hip/hip_runtime.h>
#include <stdint.h>

#define DEV __device__ __forceinline__

typedef unsigned short u16;
typedef unsigned int u32;

// ---------- bf16 helpers (bf16 = top 16 bits of f32, RNE on pack) ----------
DEV float bf2f(u16 v){ return __uint_as_float(((u32)v)<<16); }
DEV u16 f2bf(float f){
    u32 x = __float_as_uint(f);
    x += 0x7fffu + ((x>>16)&1u);
    return (u16)(x>>16);
}
DEV void cvt8(int4 r, float* f){
    u32 a=(u32)r.x, b=(u32)r.y, c=(u32)r.z, d=(u32)r.w;
    f[0]=__uint_as_float(a<<16); f[1]=__uint_as_float(a&0xffff0000u);
    f[2]=__uint_as_float(b<<16); f[3]=__uint_as_float(b&0xffff0000u);
    f[4]=__uint_as_float(c<<16); f[5]=__uint_as_float(c&0xffff0000u);
    f[6]=__uint_as_float(d<<16); f[7]=__uint_as_float(d&0xffff0000u);
}
DEV void cvt4(int2 r, float* f){
    u32 a=(u32)r.x, b=(u32)r.y;
    f[0]=__uint_as_float(a<<16); f[1]=__uint_as_float(a&0xffff0000u);
    f[2]=__uint_as_float(b<<16); f[3]=__uint_as_float(b&0xffff0000u);
}
DEV int4 pack8(const float* f){
    int4 r;
    r.x = (int)((u32)f2bf(f[0]) | ((u32)f2bf(f[1])<<16));
    r.y = (int)((u32)f2bf(f[2]) | ((u32)f2bf(f[3])<<16));
    r.z = (int)((u32)f2bf(f[4]) | ((u32)f2bf(f[5])<<16));
    r.w = (int)((u32)f2bf(f[6]) | ((u32)f2bf(f[7])<<16));
    return r;
}

// Problem constants: BSZ=1, S=256, C=128, H=4, D=32, F=64.
// tokens T=65536 (row=t>>8, n=t&255), groups g=row*4+h in [0,1024)

// Param block layout (elements, bf16) inside workspace:
#define P_LNW 0
#define P_LNB 128
#define P_QW  256
#define P_QB  16640
#define P_KW  16768
#define P_KB  33152
#define P_VW  33280
#define P_VB  49664
#define P_QFW 49792
#define P_QFB 50816
#define P_KFW 50848
#define P_KFB 51872
#define P_GW  51904
#define P_GB  68288
#define P_OW  68416
#define P_OB  84800
#define P_TOT 84928

// ---------------- dtype detect: flag=1 if inputs are bf16, 0 if f32 ----------------
__global__ void detect_kernel(const u32* __restrict__ z, u32* __restrict__ flag){
    int tid = threadIdx.x;
    u32 w = z[(size_t)tid*997];
    u32 b0 = w & 0xFFFFu;                    // low half: genuine bf16 iff input is bf16
    int e = (int)((b0>>7)&0xFF);
    int good = (e>=96 && e<=150) ? 1 : 0;    // plausible exponent for ~N(0,1) data
    __shared__ int red[4];
    #pragma unroll
    for(int o=1;o<64;o<<=1) good += __shfl_xor(good,o,64);
    if((tid&63)==0) red[tid>>6]=good;
    __syncthreads();
    if(tid==0) *flag = ((red[0]+red[1]+red[2]+red[3]) > 192) ? 1u : 0u;
}

// ---------------- convert all params to bf16 param block ----------------
__global__ void convert_params(
    const void* p0, const void* p1, const void* p2, const void* p3,
    const void* p4, const void* p5, const void* p6, const void* p7,
    const void* p8, const void* p9, const void* p10, const void* p11,
    const void* p12, const void* p13, const void* p14, const void* p15,
    const u32* __restrict__ flag, u16* __restrict__ dst){
    int idx = blockIdx.x*256 + threadIdx.x;
    if(idx >= P_TOT) return;
    const int offs[17] = {P_LNW,P_LNB,P_QW,P_QB,P_KW,P_KB,P_VW,P_VB,
                          P_QFW,P_QFB,P_KFW,P_KFB,P_GW,P_GB,P_OW,P_OB,P_TOT};
    const void* ptrs[16] = {p0,p1,p2,p3,p4,p5,p6,p7,p8,p9,p10,p11,p12,p13,p14,p15};
    int tsel = 0;
    #pragma unroll
    for(int i=1;i<16;++i) if(idx >= offs[i]) tsel = i;
    int local = idx - offs[tsel];
    u16 v;
    if(*flag) v = ((const u16*)ptrs[tsel])[local];
    else      v = f2bf(((const float*)ptrs[tsel])[local]);
    dst[idx] = v;
}

// ---------------- LayerNorm: one wave per token, dtype-flag on z loads ----------------
__global__ void ln_kernel(const void* __restrict__ zv, const u16* __restrict__ pb,
                          const u32* __restrict__ flag, u16* __restrict__ zn){
    int t = blockIdx.x*4 + (threadIdx.x>>6);
    int lane = threadIdx.x & 63;
    float x0, x1;
    if(*flag){
        u32 pr = ((const u32*)zv)[(size_t)t*64 + lane];
        x0 = __uint_as_float(pr<<16); x1 = __uint_as_float(pr & 0xffff0000u);
    } else {
        float2 v = ((const float2*)zv)[(size_t)t*64 + lane];
        x0 = v.x; x1 = v.y;
    }
    float s = x0 + x1, s2 = x0*x0 + x1*x1;
    #pragma unroll
    for(int o=1;o<64;o<<=1){ s += __shfl_xor(s,o,64); s2 += __shfl_xor(s2,o,64); }
    float mean = s*(1.f/128.f);
    float var  = s2*(1.f/128.f) - mean*mean;
    float rs = rsqrtf(var + 1e-5f);
    int c0 = 2*lane;
    float w0 = bf2f(pb[P_LNW+c0]), w1 = bf2f(pb[P_LNW+c0+1]);
    float b0 = bf2f(pb[P_LNB+c0]), b1 = bf2f(pb[P_LNB+c0+1]);
    float o0 = (x0-mean)*rs*w0 + b0;
    float o1 = (x1-mean)*rs*w1 + b1;
    u32 po = (u32)f2bf(o0) | ((u32)f2bf(o1)<<16);
    *(u32*)(zn + (size_t)t*128 + c0) = po;
}

// ---------------- GEMM: out[m][n] = A[m][:]·W[n][:] + b[n], M=65536, N=K=128 ----------------
enum { EPI_PLAIN=0, EPI_MASK=1, EPI_SIG=2 };

template<int EPI, bool DUAL>
__global__ __launch_bounds__(256,2)
void gemm128(const u16* __restrict__ A, const u16* __restrict__ W,
             const u16* __restrict__ bias, void* __restrict__ out,
             const int* __restrict__ mask, const u32* __restrict__ flagp){
    __shared__ int4 a_sw[2048];   // [m][16 chunks], phys chunk = c ^ ((m>>3)&15)
    __shared__ int4 w_sw[2048];
    int tid = threadIdx.x;
    int m0 = blockIdx.x * 128;
    const int4* Ag = (const int4*)A + (size_t)m0*16;
    const int4* Wg = (const int4*)W;
    #pragma unroll
    for(int it=0; it<8; ++it){
        int j = it*256 + tid;
        int m = j>>4, c = j&15;
        int ph = m*16 + (c ^ ((m>>3)&15));
        a_sw[ph] = Ag[j];
        w_sw[ph] = Wg[j];
    }
    __syncthreads();
    int ng = tid & 15, mg = tid >> 4;
    float acc[8][8];
    #pragma unroll
    for(int i=0;i<8;++i)
        #pragma unroll
        for(int j=0;j<8;++j) acc[i][j] = 0.f;
    for(int c=0; c<16; ++c){
        float wf[8][8];
        #pragma unroll
        for(int j=0;j<8;++j) cvt8(w_sw[(ng*8+j)*16 + (c^ng)], wf[j]);
        #pragma unroll
        for(int i=0;i<8;++i){
            float af[8];
            cvt8(a_sw[(mg*8+i)*16 + (c^mg)], af);
            #pragma unroll
            for(int u=0;u<8;++u)
                #pragma unroll
                for(int j=0;j<8;++j)
                    acc[i][j] = fmaf(af[u], wf[j][u], acc[i][j]);
        }
    }
    float bv[8];
    #pragma unroll
    for(int j=0;j<8;++j) bv[j] = bf2f(bias[ng*8+j]);
    bool isf32 = DUAL ? (*flagp == 0u) : false;
    #pragma unroll
    for(int i=0;i<8;++i){
        int m = m0 + mg*8 + i;
        float mk = 1.f;
        if(EPI==EPI_MASK) mk = (float)mask[m];
        float o[8];
        #pragma unroll
        for(int j=0;j<8;++j){
            float v = acc[i][j] + bv[j];
            if(EPI==EPI_SIG)  v = 1.f/(1.f + __expf(-v));
            if(EPI==EPI_MASK) v *= mk;
            o[j] = v;
        }
        if(DUAL && isf32){
            float4 lo; lo.x=o[0]; lo.y=o[1]; lo.z=o[2]; lo.w=o[3];
            float4 hi; hi.x=o[4]; hi.y=o[5]; hi.z=o[6]; hi.w=o[7];
            ((float4*)out)[(size_t)m*32 + ng*2    ] = lo;
            ((float4*)out)[(size_t)m*32 + ng*2 + 1] = hi;
        } else {
            ((int4*)out)[(size_t)m*16 + ng] = pack8(o);
        }
    }
}

// ---------------- kv + ksum with fused feature map: one block per (row,h) ----------------
// kf[n][j]=exp(clip(k_h[n]·fw[j]+fb[j]))·mask, kf[n][j+32]=exp(-·)·mask
// kv[f][d] = sum_n kf[n][f]*v_h[n][d]; ksum[f] = sum_n kf[n][f]
__global__ __launch_bounds__(256)
void kv_kernel(const u16* __restrict__ k, const u16* __restrict__ v,
               const int* __restrict__ mask, const u16* __restrict__ pb,
               float* __restrict__ kv, float* __restrict__ ksum){
    __shared__ float k_f32[64*36];
    __shared__ u16 kf_c[64*68];
    __shared__ u16 v_c[64*32];
    int g = blockIdx.x, row = g>>2, h = g&3;
    int tid = threadIdx.x;
    int j = tid & 31, np = tid >> 5;
    float wreg[32];
    #pragma unroll
    for(int d=0; d<32; ++d) wreg[d] = bf2f(pb[P_KFW + j*32 + d]);
    float bj = bf2f(pb[P_KFB + j]);
    int fq = tid >> 4, dd = tid & 15;          // f = fq*4+i, d = dd*2+{0,1}
    float acc[4][2]; float ks[4];
    #pragma unroll
    for(int i=0;i<4;++i){ ks[i]=0.f; acc[i][0]=0.f; acc[i][1]=0.f; }
    for(int ch=0; ch<4; ++ch){
        int n0 = ch*64;
        {   int n = tid>>2, qd = tid&3;
            int4 r = *((const int4*)(k + (size_t)(row*256 + n0 + n)*128 + h*32) + qd);
            float f[8]; cvt8(r, f);
            #pragma unroll
            for(int u=0;u<8;++u) k_f32[n*36 + qd*8 + u] = f[u];
            int4 rv = *((const int4*)(v + (size_t)(row*256 + n0 + n)*128 + h*32) + qd);
            *(int4*)(v_c + n*32 + qd*8) = rv;
        }
        __syncthreads();
        #pragma unroll
        for(int nn=0; nn<8; ++nn){
            int n = np*8 + nn;
            float m = bj;
            #pragma unroll
            for(int dc=0; dc<8; ++dc){
                float4 qv = *(const float4*)&k_f32[n*36 + dc*4];
                m = fmaf(qv.x, wreg[dc*4+0], m);
                m = fmaf(qv.y, wreg[dc*4+1], m);
                m = fmaf(qv.z, wreg[dc*4+2], m);
                m = fmaf(qv.w, wreg[dc*4+3], m);
            }
            m = fminf(8.f, fmaxf(-8.f, m));
            float mk = (float)mask[row*256 + n0 + n];
            kf_c[n*68 + j]      = f2bf(__expf(m)*mk);
            kf_c[n*68 + j + 32] = f2bf(__expf(-m)*mk);
        }
        __syncthreads();
        for(int n=0; n<64; ++n){
            float kfv[4]; cvt4(*(const int2*)(kf_c + n*68 + fq*4), kfv);
            u32 pv = *(const u32*)(v_c + n*32 + dd*2);
            float v0 = __uint_as_float(pv<<16), v1 = __uint_as_float(pv & 0xffff0000u);
            #pragma unroll
            for(int i=0;i<4;++i){
                ks[i] += kfv[i];
                acc[i][0] = fmaf(kfv[i], v0, acc[i][0]);
                acc[i][1] = fmaf(kfv[i], v1, acc[i][1]);
            }
        }
        __syncthreads();
    }
    #pragma unroll
    for(int i=0;i<4;++i){
        int f = fq*4 + i;
        float2 st; st.x = acc[i][0]; st.y = acc[i][1];
        *(float2*)(kv + ((size_t)g*64 + f)*32 + dd*2) = st;
        if(dd==0) ksum[(size_t)g*64 + f] = ks[i];
    }
}

// ---------------- attention with fused feature map + gate: one block per (row,h) ----------------
// out[n][d] = (sum_f qf[n][f]*kv[f][d]) / max(sum_f qf[n][f]*ksum[f],1e-6) * gate[t][h*32+d]
// NOTE: attn may alias q (we stage each chunk to LDS before overwriting it).
__global__ __launch_bounds__(256)
void attn_kernel(const u16* __restrict__ q, const float* __restrict__ kv,
                 const float* __restrict__ ksum, const u16* __restrict__ gate,
                 const u16* __restrict__ pb, u16* __restrict__ attn){
    __shared__ float q_f32[64*36];
    __shared__ u16 qf_c[64*68];
    __shared__ float kv_lds[64*32];
    __shared__ float ks_lds[64];
    int g = blockIdx.x, row = g>>2, h = g&3;
    int tid = threadIdx.x;
    #pragma unroll
    for(int it=0; it<2; ++it)
        ((float4*)kv_lds)[it*256 + tid] = ((const float4*)(kv + (size_t)g*2048))[it*256 + tid];
    if(tid < 64) ks_lds[tid] = ksum[(size_t)g*64 + tid];
    int j = tid & 31, np = tid >> 5;
    float wreg[32];
    #pragma unroll
    for(int d=0; d<32; ++d) wreg[d] = bf2f(pb[P_QFW + j*32 + d]);
    float bj = bf2f(pb[P_QFB + j]);
    int nt = tid >> 2, dg = tid & 3;           // token nt in chunk, dims dg*8..dg*8+7
    __syncthreads();
    for(int ch=0; ch<4; ++ch){
        int n0 = ch*64;
        {   int n = tid>>2, qd = tid&3;
            int4 r = *((const int4*)(q + (size_t)(row*256 + n0 + n)*128 + h*32) + qd);
            float f[8]; cvt8(r, f);
            #pragma unroll
            for(int u=0;u<8;++u) q_f32[n*36 + qd*8 + u] = f[u];
        }
        __syncthreads();
        #pragma unroll
        for(int nn=0; nn<8; ++nn){
            int n = np*8 + nn;
            float m = bj;
            #pragma unroll
            for(int dc=0; dc<8; ++dc){
                float4 qv = *(const float4*)&q_f32[n*36 + dc*4];
                m = fmaf(qv.x, wreg[dc*4+0], m);
                m = fmaf(qv.y, wreg[dc*4+1], m);
                m = fmaf(qv.z, wreg[dc*4+2], m);
                m = fmaf(qv.w, wreg[dc*4+3], m);
            }
            m = fminf(8.f, fmaxf(-8.f, m));
            qf_c[n*68 + j]      = f2bf(__expf(m));
            qf_c[n*68 + j + 32] = f2bf(__expf(-m));
        }
        __syncthreads();
        float acc[8]; float den = 0.f;
        #pragma unroll
        for(int u=0;u<8;++u) acc[u] = 0.f;
        for(int f=0; f<64; ++f){
            float qv = bf2f(qf_c[nt*68 + f]);
            den = fmaf(qv, ks_lds[f], den);
            float4 a = *(const float4*)(kv_lds + f*32 + dg*8);
            float4 b = *(const float4*)(kv_lds + f*32 + dg*8 + 4);
            acc[0] = fmaf(qv, a.x, acc[0]); acc[1] = fmaf(qv, a.y, acc[1]);
            acc[2] = fmaf(qv, a.z, acc[2]); acc[3] = fmaf(qv, a.w, acc[3]);
            acc[4] = fmaf(qv, b.x, acc[4]); acc[5] = fmaf(qv, b.y, acc[5]);
            acc[6] = fmaf(qv, b.z, acc[6]); acc[7] = fmaf(qv, b.w, acc[7]);
        }
        size_t t = (size_t)row*256 + n0 + nt;
        float dn = 1.f / fmaxf(den, 1e-6f);
        float gv[8]; cvt8(*(const int4*)(gate + t*128 + h*32 + dg*8), gv);
        float o[8];
        #pragma unroll
        for(int u=0;u<8;++u) o[u] = acc[u]*dn*gv[u];
        *(int4*)(attn + t*128 + h*32 + dg*8) = pack8(o);
        __syncthreads();
    }
}

// ---------------- launch ----------------
extern "C" void kernel_launch(void* const* d_in, const int* in_sizes, int n_in,
                              void* d_out, int out_size, void* d_ws, size_t ws_size,
                              hipStream_t stream){
    const void* z    = d_in[0];
    const int*  mask = (const int*)d_in[1];

    char* ws = (char*)d_ws;
    const size_t MB = (size_t)1<<20;
    u16*   zn   = (u16*)(ws + 0*MB);      // 16 MB  [t][128] bf16
    u16*   q    = (u16*)(ws + 16*MB);     // 16 MB  q-proj; later reused as attn
    u16*   k    = (u16*)(ws + 32*MB);     // 16 MB
    u16*   v    = (u16*)(ws + 48*MB);     // 16 MB  (masked)
    u16*   gate = (u16*)(ws + 64*MB);     // 16 MB  (sigmoid applied)
    float* kv   = (float*)(ws + 80*MB);   // 8 MB   [g][64][32] f32
    float* ksum = (float*)(ws + 88*MB);   // 256 KB [g][64] f32
    u16*   pb   = (u16*)(ws + 88*MB + 512*1024);  // ~166 KB bf16 param block
    u32*   flag = (u32*)(ws + 89*MB);     // 4 B dtype flag
    u16*   attn = q;                      // alias (safe, see attn_kernel)

    detect_kernel<<<1,256,0,stream>>>((const u32*)z, flag);
    convert_params<<<(P_TOT+255)/256,256,0,stream>>>(
        d_in[2], d_in[3], d_in[4], d_in[5], d_in[6], d_in[7], d_in[8], d_in[9],
        d_in[10], d_in[11], d_in[12], d_in[13], d_in[14], d_in[15], d_in[16], d_in[17],
        flag, pb);
    ln_kernel<<<16384,256,0,stream>>>(z, pb, flag, zn);
    gemm128<EPI_PLAIN,false><<<512,256,0,stream>>>(zn, pb+P_QW, pb+P_QB, q,    nullptr, nullptr);
    gemm128<EPI_PLAIN,false><<<512,256,0,stream>>>(zn, pb+P_KW, pb+P_KB, k,    nullptr, nullptr);
    gemm128<EPI_MASK ,false><<<512,256,0,stream>>>(zn, pb+P_VW, pb+P_VB, v,    mask,    nullptr);
    gemm128<EPI_SIG  ,false><<<512,256,0,stream>>>(zn, pb+P_GW, pb+P_GB, gate, nullptr, nullptr);
    kv_kernel<<<1024,256,0,stream>>>(k, v, mask, pb, kv, ksum);
    attn_kernel<<<1024,256,0,stream>>>(q, kv, ksum, gate, pb, attn);
    gemm128<EPI_MASK ,true ><<<512,256,0,stream>>>(attn, pb+P_OW, pb+P_OB, d_out, mask, flag);
}

// Round 3
// 277.697 us; speedup vs baseline: 1.3199x; 1.3199x over previous
//
#include <hip/hip_runtime.h>
#include <stdint.h>

#define DEV __device__ __forceinline__

typedef unsigned short u16;
typedef unsigned int u32;
typedef short bh8 __attribute__((ext_vector_type(8)));
typedef float f32x4 __attribute__((ext_vector_type(4)));

// ---------- bf16 helpers (bf16 = top 16 bits of f32, RNE on pack) ----------
DEV float bf2f(u16 v){ return __uint_as_float(((u32)v)<<16); }
DEV u16 f2bf(float f){
    u32 x = __float_as_uint(f);
    x += 0x7fffu + ((x>>16)&1u);
    return (u16)(x>>16);
}
DEV void cvt8(int4 r, float* f){
    u32 a=(u32)r.x, b=(u32)r.y, c=(u32)r.z, d=(u32)r.w;
    f[0]=__uint_as_float(a<<16); f[1]=__uint_as_float(a&0xffff0000u);
    f[2]=__uint_as_float(b<<16); f[3]=__uint_as_float(b&0xffff0000u);
    f[4]=__uint_as_float(c<<16); f[5]=__uint_as_float(c&0xffff0000u);
    f[6]=__uint_as_float(d<<16); f[7]=__uint_as_float(d&0xffff0000u);
}
DEV void cvt4(int2 r, float* f){
    u32 a=(u32)r.x, b=(u32)r.y;
    f[0]=__uint_as_float(a<<16); f[1]=__uint_as_float(a&0xffff0000u);
    f[2]=__uint_as_float(b<<16); f[3]=__uint_as_float(b&0xffff0000u);
}
DEV int4 pack8(const float* f){
    int4 r;
    r.x = (int)((u32)f2bf(f[0]) | ((u32)f2bf(f[1])<<16));
    r.y = (int)((u32)f2bf(f[2]) | ((u32)f2bf(f[3])<<16));
    r.z = (int)((u32)f2bf(f[4]) | ((u32)f2bf(f[5])<<16));
    r.w = (int)((u32)f2bf(f[6]) | ((u32)f2bf(f[7])<<16));
    return r;
}
DEV bh8 ld_frag(const u16* p){
    int4 v = *(const int4*)p;
    union{ int4 i; bh8 h; } u; u.i = v; return u.h;
}

// Problem constants: BSZ=1, S=256, C=128, H=4, D=32, F=64.
// tokens T=65536 (row=t>>8, n=t&255), groups g=row*4+h in [0,1024)

// Param block layout (elements, bf16) inside workspace:
#define P_LNW 0
#define P_LNB 128
#define P_QW  256
#define P_QB  16640
#define P_KW  16768
#define P_KB  33152
#define P_VW  33280
#define P_VB  49664
#define P_QFW 49792
#define P_QFB 50816
#define P_KFW 50848
#define P_KFB 51872
#define P_GW  51904
#define P_GB  68288
#define P_OW  68416
#define P_OB  84800
#define P_TOT 84928

// ---------------- dtype detect: flag=1 if inputs are bf16, 0 if f32 ----------------
__global__ void detect_kernel(const u32* __restrict__ z, u32* __restrict__ flag){
    int tid = threadIdx.x;
    u32 w = z[(size_t)tid*997];
    u32 b0 = w & 0xFFFFu;
    int e = (int)((b0>>7)&0xFF);
    int good = (e>=96 && e<=150) ? 1 : 0;
    __shared__ int red[4];
    #pragma unroll
    for(int o=1;o<64;o<<=1) good += __shfl_xor(good,o,64);
    if((tid&63)==0) red[tid>>6]=good;
    __syncthreads();
    if(tid==0) *flag = ((red[0]+red[1]+red[2]+red[3]) > 192) ? 1u : 0u;
}

// ---------------- convert all params to bf16 param block ----------------
__global__ void convert_params(
    const void* p0, const void* p1, const void* p2, const void* p3,
    const void* p4, const void* p5, const void* p6, const void* p7,
    const void* p8, const void* p9, const void* p10, const void* p11,
    const void* p12, const void* p13, const void* p14, const void* p15,
    const u32* __restrict__ flag, u16* __restrict__ dst){
    int idx = blockIdx.x*256 + threadIdx.x;
    if(idx >= P_TOT) return;
    const int offs[17] = {P_LNW,P_LNB,P_QW,P_QB,P_KW,P_KB,P_VW,P_VB,
                          P_QFW,P_QFB,P_KFW,P_KFB,P_GW,P_GB,P_OW,P_OB,P_TOT};
    const void* ptrs[16] = {p0,p1,p2,p3,p4,p5,p6,p7,p8,p9,p10,p11,p12,p13,p14,p15};
    int tsel = 0;
    #pragma unroll
    for(int i=1;i<16;++i) if(idx >= offs[i]) tsel = i;
    int local = idx - offs[tsel];
    u16 v;
    if(*flag) v = ((const u16*)ptrs[tsel])[local];
    else      v = f2bf(((const float*)ptrs[tsel])[local]);
    dst[idx] = v;
}

// ---------------- LayerNorm: one wave per token ----------------
__global__ void ln_kernel(const void* __restrict__ zv, const u16* __restrict__ pb,
                          const u32* __restrict__ flag, u16* __restrict__ zn){
    int t = blockIdx.x*4 + (threadIdx.x>>6);
    int lane = threadIdx.x & 63;
    float x0, x1;
    if(*flag){
        u32 pr = ((const u32*)zv)[(size_t)t*64 + lane];
        x0 = __uint_as_float(pr<<16); x1 = __uint_as_float(pr & 0xffff0000u);
    } else {
        float2 v = ((const float2*)zv)[(size_t)t*64 + lane];
        x0 = v.x; x1 = v.y;
    }
    float s = x0 + x1, s2 = x0*x0 + x1*x1;
    #pragma unroll
    for(int o=1;o<64;o<<=1){ s += __shfl_xor(s,o,64); s2 += __shfl_xor(s2,o,64); }
    float mean = s*(1.f/128.f);
    float var  = s2*(1.f/128.f) - mean*mean;
    float rs = rsqrtf(var + 1e-5f);
    int c0 = 2*lane;
    float w0 = bf2f(pb[P_LNW+c0]), w1 = bf2f(pb[P_LNW+c0+1]);
    float b0 = bf2f(pb[P_LNB+c0]), b1 = bf2f(pb[P_LNB+c0+1]);
    float o0 = (x0-mean)*rs*w0 + b0;
    float o1 = (x1-mean)*rs*w1 + b1;
    u32 po = (u32)f2bf(o0) | ((u32)f2bf(o1)<<16);
    *(u32*)(zn + (size_t)t*128 + c0) = po;
}

// ---------------- MFMA proj: zn -> q, k, v*mask, sigmoid(gate) ----------------
// 128x128 tile per block; 4 waves each own a 64x64 quadrant (4x4 16x16 tiles).
// a-frags (zn rows) held in VGPRs across all 4 weight matrices.
// A-frag: lane holds A[m=lane&15][k=quad*8+j]; B-frag: W[n=lane&15][k=quad*8+j];
// C/D: col=lane&15, row=quad*4+reg.
#define LDS_P 136   // u16 row stride of transpose buffer (16B-aligned rows)
__global__ __launch_bounds__(256,2)
void proj4_kernel(const u16* __restrict__ zn, const u16* __restrict__ pb,
                  const int* __restrict__ mask,
                  u16* __restrict__ q, u16* __restrict__ k,
                  u16* __restrict__ v, u16* __restrict__ gate){
    __shared__ u16 st[128*LDS_P];
    int tid = threadIdx.x;
    int lane = tid&63, wv = tid>>6;
    int mhalf = (wv>>1)*64, nhalf = (wv&1)*64;
    int lm = lane&15, quad = lane>>4;
    int m0 = blockIdx.x*128;

    bh8 a[4][4];
    const u16* Abase = zn + (size_t)(m0 + mhalf + lm)*128 + quad*8;
    #pragma unroll
    for(int mt=0; mt<4; ++mt)
        #pragma unroll
        for(int ks=0; ks<4; ++ks)
            a[mt][ks] = ld_frag(Abase + (size_t)mt*16*128 + ks*32);

    const int WOFF[4] = {P_QW, P_KW, P_VW, P_GW};
    const int BOFF[4] = {P_QB, P_KB, P_VB, P_GB};
    u16* const outs[4] = {q, k, v, gate};

    #pragma unroll
    for(int iw=0; iw<4; ++iw){
        const u16* W = pb + WOFF[iw];
        f32x4 acc[4][4];
        #pragma unroll
        for(int mt=0;mt<4;++mt)
            #pragma unroll
            for(int nt=0;nt<4;++nt)
                acc[mt][nt] = (f32x4){0.f,0.f,0.f,0.f};
        #pragma unroll
        for(int ks=0; ks<4; ++ks){
            bh8 b[4];
            #pragma unroll
            for(int nt=0; nt<4; ++nt)
                b[nt] = ld_frag(W + (size_t)(nhalf + nt*16 + lm)*128 + ks*32 + quad*8);
            #pragma unroll
            for(int mt=0; mt<4; ++mt)
                #pragma unroll
                for(int nt=0; nt<4; ++nt)
                    acc[mt][nt] = __builtin_amdgcn_mfma_f32_16x16x32_bf16(
                        a[mt][ks], b[nt], acc[mt][nt], 0, 0, 0);
        }
        float bv[4];
        #pragma unroll
        for(int nt=0; nt<4; ++nt) bv[nt] = bf2f(pb[BOFF[iw] + nhalf + nt*16 + lm]);
        #pragma unroll
        for(int mt=0; mt<4; ++mt){
            int mrow = m0 + mhalf + mt*16 + quad*4;
            float mk[4];
            if(iw==2){
                #pragma unroll
                for(int r=0;r<4;++r) mk[r] = (float)mask[mrow+r];
            }
            #pragma unroll
            for(int nt=0; nt<4; ++nt){
                #pragma unroll
                for(int r=0; r<4; ++r){
                    float x = acc[mt][nt][r] + bv[nt];
                    if(iw==3) x = 1.f/(1.f + __expf(-x));
                    if(iw==2) x *= mk[r];
                    st[(mhalf + mt*16 + quad*4 + r)*LDS_P + nhalf + nt*16 + lm] = f2bf(x);
                }
            }
        }
        __syncthreads();
        {   // coalesced read-back: 2 threads per row, 8 int4 each
            int row = tid>>1, half = tid&1;
            const u16* src = st + row*LDS_P + half*64;
            u16* dst = outs[iw] + (size_t)(m0 + row)*128 + half*64;
            #pragma unroll
            for(int it=0; it<8; ++it)
                ((int4*)dst)[it] = ((const int4*)src)[it];
        }
        __syncthreads();
    }
}

// ---------------- MFMA o-proj: attn -> out (x mask, dual dtype store) ----------------
__global__ __launch_bounds__(256,2)
void oproj_kernel(const u16* __restrict__ attn, const u16* __restrict__ pb,
                  const int* __restrict__ mask, const u32* __restrict__ flagp,
                  void* __restrict__ out){
    __shared__ u16 st[128*LDS_P];
    int tid = threadIdx.x;
    int lane = tid&63, wv = tid>>6;
    int mhalf = (wv>>1)*64, nhalf = (wv&1)*64;
    int lm = lane&15, quad = lane>>4;
    int m0 = blockIdx.x*128;

    f32x4 acc[4][4];
    #pragma unroll
    for(int mt=0;mt<4;++mt)
        #pragma unroll
        for(int nt=0;nt<4;++nt)
            acc[mt][nt] = (f32x4){0.f,0.f,0.f,0.f};

    const u16* Abase = attn + (size_t)(m0 + mhalf + lm)*128 + quad*8;
    const u16* W = pb + P_OW;
    #pragma unroll
    for(int ks=0; ks<4; ++ks){
        bh8 a[4], b[4];
        #pragma unroll
        for(int mt=0; mt<4; ++mt)
            a[mt] = ld_frag(Abase + (size_t)mt*16*128 + ks*32);
        #pragma unroll
        for(int nt=0; nt<4; ++nt)
            b[nt] = ld_frag(W + (size_t)(nhalf + nt*16 + lm)*128 + ks*32 + quad*8);
        #pragma unroll
        for(int mt=0; mt<4; ++mt)
            #pragma unroll
            for(int nt=0; nt<4; ++nt)
                acc[mt][nt] = __builtin_amdgcn_mfma_f32_16x16x32_bf16(
                    a[mt], b[nt], acc[mt][nt], 0, 0, 0);
    }
    float bv[4];
    #pragma unroll
    for(int nt=0; nt<4; ++nt) bv[nt] = bf2f(pb[P_OB + nhalf + nt*16 + lm]);
    #pragma unroll
    for(int mt=0; mt<4; ++mt){
        int mrow = m0 + mhalf + mt*16 + quad*4;
        float mk[4];
        #pragma unroll
        for(int r=0;r<4;++r) mk[r] = (float)mask[mrow+r];
        #pragma unroll
        for(int nt=0; nt<4; ++nt)
            #pragma unroll
            for(int r=0; r<4; ++r){
                float x = (acc[mt][nt][r] + bv[nt]) * mk[r];
                st[(mhalf + mt*16 + quad*4 + r)*LDS_P + nhalf + nt*16 + lm] = f2bf(x);
            }
    }
    __syncthreads();
    {
        int row = tid>>1, half = tid&1;
        const u16* src = st + row*LDS_P + half*64;
        bool isbf = (*flagp != 0u);
        if(isbf){
            u16* dst = (u16*)out + (size_t)(m0 + row)*128 + half*64;
            #pragma unroll
            for(int it=0; it<8; ++it)
                ((int4*)dst)[it] = ((const int4*)src)[it];
        } else {
            float* dst = (float*)out + (size_t)(m0 + row)*128 + half*64;
            #pragma unroll
            for(int it=0; it<8; ++it){
                float f[8]; cvt8(((const int4*)src)[it], f);
                float4 lo; lo.x=f[0]; lo.y=f[1]; lo.z=f[2]; lo.w=f[3];
                float4 hi; hi.x=f[4]; hi.y=f[5]; hi.z=f[6]; hi.w=f[7];
                ((float4*)dst)[it*2  ] = lo;
                ((float4*)dst)[it*2+1] = hi;
            }
        }
    }
}

// ---------------- kv + ksum with fused feature map: one block per (row,h) ----------------
__global__ __launch_bounds__(256)
void kv_kernel(const u16* __restrict__ k, const u16* __restrict__ v,
               const int* __restrict__ mask, const u16* __restrict__ pb,
               float* __restrict__ kv, float* __restrict__ ksum){
    __shared__ float k_f32[64*36];
    __shared__ u16 kf_c[64*68];
    __shared__ u16 v_c[64*32];
    int g = blockIdx.x, row = g>>2, h = g&3;
    int tid = threadIdx.x;
    int j = tid & 31, np = tid >> 5;
    float wreg[32];
    #pragma unroll
    for(int d=0; d<32; ++d) wreg[d] = bf2f(pb[P_KFW + j*32 + d]);
    float bj = bf2f(pb[P_KFB + j]);
    int fq = tid >> 4, dd = tid & 15;
    float acc[4][2]; float ks[4];
    #pragma unroll
    for(int i=0;i<4;++i){ ks[i]=0.f; acc[i][0]=0.f; acc[i][1]=0.f; }
    for(int ch=0; ch<4; ++ch){
        int n0 = ch*64;
        {   int n = tid>>2, qd = tid&3;
            int4 r = *((const int4*)(k + (size_t)(row*256 + n0 + n)*128 + h*32) + qd);
            float f[8]; cvt8(r, f);
            #pragma unroll
            for(int u=0;u<8;++u) k_f32[n*36 + qd*8 + u] = f[u];
            int4 rv = *((const int4*)(v + (size_t)(row*256 + n0 + n)*128 + h*32) + qd);
            *(int4*)(v_c + n*32 + qd*8) = rv;
        }
        __syncthreads();
        #pragma unroll
        for(int nn=0; nn<8; ++nn){
            int n = np*8 + nn;
            float m = bj;
            #pragma unroll
            for(int dc=0; dc<8; ++dc){
                float4 qv = *(const float4*)&k_f32[n*36 + dc*4];
                m = fmaf(qv.x, wreg[dc*4+0], m);
                m = fmaf(qv.y, wreg[dc*4+1], m);
                m = fmaf(qv.z, wreg[dc*4+2], m);
                m = fmaf(qv.w, wreg[dc*4+3], m);
            }
            m = fminf(8.f, fmaxf(-8.f, m));
            float mk = (float)mask[row*256 + n0 + n];
            kf_c[n*68 + j]      = f2bf(__expf(m)*mk);
            kf_c[n*68 + j + 32] = f2bf(__expf(-m)*mk);
        }
        __syncthreads();
        for(int n=0; n<64; ++n){
            float kfv[4]; cvt4(*(const int2*)(kf_c + n*68 + fq*4), kfv);
            u32 pv = *(const u32*)(v_c + n*32 + dd*2);
            float v0 = __uint_as_float(pv<<16), v1 = __uint_as_float(pv & 0xffff0000u);
            #pragma unroll
            for(int i=0;i<4;++i){
                ks[i] += kfv[i];
                acc[i][0] = fmaf(kfv[i], v0, acc[i][0]);
                acc[i][1] = fmaf(kfv[i], v1, acc[i][1]);
            }
        }
        __syncthreads();
    }
    #pragma unroll
    for(int i=0;i<4;++i){
        int f = fq*4 + i;
        float2 st2; st2.x = acc[i][0]; st2.y = acc[i][1];
        *(float2*)(kv + ((size_t)g*64 + f)*32 + dd*2) = st2;
        if(dd==0) ksum[(size_t)g*64 + f] = ks[i];
    }
}

// ---------------- attention with fused feature map + gate ----------------
__global__ __launch_bounds__(256)
void attn_kernel(const u16* __restrict__ q, const float* __restrict__ kv,
                 const float* __restrict__ ksum, const u16* __restrict__ gate,
                 const u16* __restrict__ pb, u16* __restrict__ attn){
    __shared__ float q_f32[64*36];
    __shared__ u16 qf_c[64*68];
    __shared__ float kv_lds[64*32];
    __shared__ float ks_lds[64];
    int g = blockIdx.x, row = g>>2, h = g&3;
    int tid = threadIdx.x;
    #pragma unroll
    for(int it=0; it<2; ++it)
        ((float4*)kv_lds)[it*256 + tid] = ((const float4*)(kv + (size_t)g*2048))[it*256 + tid];
    if(tid < 64) ks_lds[tid] = ksum[(size_t)g*64 + tid];
    int j = tid & 31, np = tid >> 5;
    float wreg[32];
    #pragma unroll
    for(int d=0; d<32; ++d) wreg[d] = bf2f(pb[P_QFW + j*32 + d]);
    float bj = bf2f(pb[P_QFB + j]);
    int nt = tid >> 2, dg = tid & 3;
    __syncthreads();
    for(int ch=0; ch<4; ++ch){
        int n0 = ch*64;
        {   int n = tid>>2, qd = tid&3;
            int4 r = *((const int4*)(q + (size_t)(row*256 + n0 + n)*128 + h*32) + qd);
            float f[8]; cvt8(r, f);
            #pragma unroll
            for(int u=0;u<8;++u) q_f32[n*36 + qd*8 + u] = f[u];
        }
        __syncthreads();
        #pragma unroll
        for(int nn=0; nn<8; ++nn){
            int n = np*8 + nn;
            float m = bj;
            #pragma unroll
            for(int dc=0; dc<8; ++dc){
                float4 qv = *(const float4*)&q_f32[n*36 + dc*4];
                m = fmaf(qv.x, wreg[dc*4+0], m);
                m = fmaf(qv.y, wreg[dc*4+1], m);
                m = fmaf(qv.z, wreg[dc*4+2], m);
                m = fmaf(qv.w, wreg[dc*4+3], m);
            }
            m = fminf(8.f, fmaxf(-8.f, m));
            qf_c[n*68 + j]      = f2bf(__expf(m));
            qf_c[n*68 + j + 32] = f2bf(__expf(-m));
        }
        __syncthreads();
        float acc[8]; float den = 0.f;
        #pragma unroll
        for(int u=0;u<8;++u) acc[u] = 0.f;
        for(int f=0; f<64; ++f){
            float qv = bf2f(qf_c[nt*68 + f]);
            den = fmaf(qv, ks_lds[f], den);
            float4 a4 = *(const float4*)(kv_lds + f*32 + dg*8);
            float4 b4 = *(const float4*)(kv_lds + f*32 + dg*8 + 4);
            acc[0] = fmaf(qv, a4.x, acc[0]); acc[1] = fmaf(qv, a4.y, acc[1]);
            acc[2] = fmaf(qv, a4.z, acc[2]); acc[3] = fmaf(qv, a4.w, acc[3]);
            acc[4] = fmaf(qv, b4.x, acc[4]); acc[5] = fmaf(qv, b4.y, acc[5]);
            acc[6] = fmaf(qv, b4.z, acc[6]); acc[7] = fmaf(qv, b4.w, acc[7]);
        }
        size_t t = (size_t)row*256 + n0 + nt;
        float dn = 1.f / fmaxf(den, 1e-6f);
        float gv[8]; cvt8(*(const int4*)(gate + t*128 + h*32 + dg*8), gv);
        float o[8];
        #pragma unroll
        for(int u=0;u<8;++u) o[u] = acc[u]*dn*gv[u];
        *(int4*)(attn + t*128 + h*32 + dg*8) = pack8(o);
        __syncthreads();
    }
}

// ---------------- launch ----------------
extern "C" void kernel_launch(void* const* d_in, const int* in_sizes, int n_in,
                              void* d_out, int out_size, void* d_ws, size_t ws_size,
                              hipStream_t stream){
    const void* z    = d_in[0];
    const int*  mask = (const int*)d_in[1];

    char* ws = (char*)d_ws;
    const size_t MB = (size_t)1<<20;
    u16*   zn   = (u16*)(ws + 0*MB);      // 16 MB  [t][128] bf16
    u16*   q    = (u16*)(ws + 16*MB);     // 16 MB  q-proj; later reused as attn
    u16*   k    = (u16*)(ws + 32*MB);     // 16 MB
    u16*   v    = (u16*)(ws + 48*MB);     // 16 MB  (masked)
    u16*   gate = (u16*)(ws + 64*MB);     // 16 MB  (sigmoid applied)
    float* kv   = (float*)(ws + 80*MB);   // 8 MB   [g][64][32] f32
    float* ksum = (float*)(ws + 88*MB);   // 256 KB [g][64] f32
    u16*   pb   = (u16*)(ws + 88*MB + 512*1024);  // ~166 KB bf16 param block
    u32*   flag = (u32*)(ws + 89*MB);     // 4 B dtype flag
    u16*   attn = q;                      // alias (safe: attn_kernel stages q chunk to LDS first)

    detect_kernel<<<1,256,0,stream>>>((const u32*)z, flag);
    convert_params<<<(P_TOT+255)/256,256,0,stream>>>(
        d_in[2], d_in[3], d_in[4], d_in[5], d_in[6], d_in[7], d_in[8], d_in[9],
        d_in[10], d_in[11], d_in[12], d_in[13], d_in[14], d_in[15], d_in[16], d_in[17],
        flag, pb);
    ln_kernel<<<16384,256,0,stream>>>(z, pb, flag, zn);
    proj4_kernel<<<512,256,0,stream>>>(zn, pb, mask, q, k, v, gate);
    kv_kernel<<<1024,256,0,stream>>>(k, v, mask, pb, kv, ksum);
    attn_kernel<<<1024,256,0,stream>>>(q, kv, ksum, gate, pb, attn);
    oproj_kernel<<<512,256,0,stream>>>(attn, pb, mask, flag, d_out);
}

// Round 4
// 217.482 us; speedup vs baseline: 1.6854x; 1.2769x over previous
//
#include <hip/hip_runtime.h>
#include <stdint.h>

#define DEV __device__ __forceinline__

typedef unsigned short u16;
typedef unsigned int u32;
typedef short bh8 __attribute__((ext_vector_type(8)));
typedef float f32x4 __attribute__((ext_vector_type(4)));

// ---------- bf16 helpers (bf16 = top 16 bits of f32, RNE on pack) ----------
DEV float bf2f(u16 v){ return __uint_as_float(((u32)v)<<16); }
DEV u16 f2bf(float f){
    u32 x = __float_as_uint(f);
    x += 0x7fffu + ((x>>16)&1u);
    return (u16)(x>>16);
}
DEV void cvt8(int4 r, float* f){
    u32 a=(u32)r.x, b=(u32)r.y, c=(u32)r.z, d=(u32)r.w;
    f[0]=__uint_as_float(a<<16); f[1]=__uint_as_float(a&0xffff0000u);
    f[2]=__uint_as_float(b<<16); f[3]=__uint_as_float(b&0xffff0000u);
    f[4]=__uint_as_float(c<<16); f[5]=__uint_as_float(c&0xffff0000u);
    f[6]=__uint_as_float(d<<16); f[7]=__uint_as_float(d&0xffff0000u);
}
DEV int4 pack8(const float* f){
    int4 r;
    r.x = (int)((u32)f2bf(f[0]) | ((u32)f2bf(f[1])<<16));
    r.y = (int)((u32)f2bf(f[2]) | ((u32)f2bf(f[3])<<16));
    r.z = (int)((u32)f2bf(f[4]) | ((u32)f2bf(f[5])<<16));
    r.w = (int)((u32)f2bf(f[6]) | ((u32)f2bf(f[7])<<16));
    return r;
}
DEV bh8 ld_frag(const u16* p){
    int4 v = *(const int4*)p;
    union{ int4 i; bh8 h; } u; u.i = v; return u.h;
}
#define MFMA __builtin_amdgcn_mfma_f32_16x16x32_bf16

// Problem constants: BSZ=1, S=256, C=128, H=4, D=32, F=64.
// tokens T=65536 (row=t>>8, n=t&255), groups g=row*4+h in [0,1024)

// Param block layout (elements, bf16) inside workspace:
#define P_LNW 0
#define P_LNB 128
#define P_QW  256
#define P_QB  16640
#define P_KW  16768
#define P_KB  33152
#define P_VW  33280
#define P_VB  49664
#define P_QFW 49792
#define P_QFB 50816
#define P_KFW 50848
#define P_KFB 51872
#define P_GW  51904
#define P_GB  68288
#define P_OW  68416
#define P_OB  84800
#define P_TOT 84928

// ---------------- dtype detect: flag=1 if inputs are bf16, 0 if f32 ----------------
__global__ void detect_kernel(const u32* __restrict__ z, u32* __restrict__ flag){
    int tid = threadIdx.x;
    u32 w = z[(size_t)tid*997];
    u32 b0 = w & 0xFFFFu;
    int e = (int)((b0>>7)&0xFF);
    int good = (e>=96 && e<=150) ? 1 : 0;
    __shared__ int red[4];
    #pragma unroll
    for(int o=1;o<64;o<<=1) good += __shfl_xor(good,o,64);
    if((tid&63)==0) red[tid>>6]=good;
    __syncthreads();
    if(tid==0) *flag = ((red[0]+red[1]+red[2]+red[3]) > 192) ? 1u : 0u;
}

// ---------------- convert all params to bf16 param block ----------------
__global__ void convert_params(
    const void* p0, const void* p1, const void* p2, const void* p3,
    const void* p4, const void* p5, const void* p6, const void* p7,
    const void* p8, const void* p9, const void* p10, const void* p11,
    const void* p12, const void* p13, const void* p14, const void* p15,
    const u32* __restrict__ flag, u16* __restrict__ dst){
    int idx = blockIdx.x*256 + threadIdx.x;
    if(idx >= P_TOT) return;
    const int offs[17] = {P_LNW,P_LNB,P_QW,P_QB,P_KW,P_KB,P_VW,P_VB,
                          P_QFW,P_QFB,P_KFW,P_KFB,P_GW,P_GB,P_OW,P_OB,P_TOT};
    const void* ptrs[16] = {p0,p1,p2,p3,p4,p5,p6,p7,p8,p9,p10,p11,p12,p13,p14,p15};
    int tsel = 0;
    #pragma unroll
    for(int i=1;i<16;++i) if(idx >= offs[i]) tsel = i;
    int local = idx - offs[tsel];
    u16 v;
    if(*flag) v = ((const u16*)ptrs[tsel])[local];
    else      v = f2bf(((const float*)ptrs[tsel])[local]);
    dst[idx] = v;
}

// ---------------- LayerNorm: one wave per token ----------------
__global__ void ln_kernel(const void* __restrict__ zv, const u16* __restrict__ pb,
                          const u32* __restrict__ flag, u16* __restrict__ zn){
    int t = blockIdx.x*4 + (threadIdx.x>>6);
    int lane = threadIdx.x & 63;
    float x0, x1;
    if(*flag){
        u32 pr = ((const u32*)zv)[(size_t)t*64 + lane];
        x0 = __uint_as_float(pr<<16); x1 = __uint_as_float(pr & 0xffff0000u);
    } else {
        float2 v = ((const float2*)zv)[(size_t)t*64 + lane];
        x0 = v.x; x1 = v.y;
    }
    float s = x0 + x1, s2 = x0*x0 + x1*x1;
    #pragma unroll
    for(int o=1;o<64;o<<=1){ s += __shfl_xor(s,o,64); s2 += __shfl_xor(s2,o,64); }
    float mean = s*(1.f/128.f);
    float var  = s2*(1.f/128.f) - mean*mean;
    float rs = rsqrtf(var + 1e-5f);
    int c0 = 2*lane;
    float w0 = bf2f(pb[P_LNW+c0]), w1 = bf2f(pb[P_LNW+c0+1]);
    float b0 = bf2f(pb[P_LNB+c0]), b1 = bf2f(pb[P_LNB+c0+1]);
    float o0 = (x0-mean)*rs*w0 + b0;
    float o1 = (x1-mean)*rs*w1 + b1;
    u32 po = (u32)f2bf(o0) | ((u32)f2bf(o1)<<16);
    *(u32*)(zn + (size_t)t*128 + c0) = po;
}

// ---------------- MFMA proj: zn -> q, k, v*mask, sigmoid(gate) ----------------
#define LDS_P 136
__global__ __launch_bounds__(256,2)
void proj4_kernel(const u16* __restrict__ zn, const u16* __restrict__ pb,
                  const int* __restrict__ mask,
                  u16* __restrict__ q, u16* __restrict__ k,
                  u16* __restrict__ v, u16* __restrict__ gate){
    __shared__ u16 st[128*LDS_P];
    int tid = threadIdx.x;
    int lane = tid&63, wv = tid>>6;
    int mhalf = (wv>>1)*64, nhalf = (wv&1)*64;
    int lm = lane&15, quad = lane>>4;
    int m0 = blockIdx.x*128;

    bh8 a[4][4];
    const u16* Abase = zn + (size_t)(m0 + mhalf + lm)*128 + quad*8;
    #pragma unroll
    for(int mt=0; mt<4; ++mt)
        #pragma unroll
        for(int ks=0; ks<4; ++ks)
            a[mt][ks] = ld_frag(Abase + (size_t)mt*16*128 + ks*32);

    const int WOFF[4] = {P_QW, P_KW, P_VW, P_GW};
    const int BOFF[4] = {P_QB, P_KB, P_VB, P_GB};
    u16* const outs[4] = {q, k, v, gate};

    #pragma unroll
    for(int iw=0; iw<4; ++iw){
        const u16* W = pb + WOFF[iw];
        f32x4 acc[4][4];
        #pragma unroll
        for(int mt=0;mt<4;++mt)
            #pragma unroll
            for(int nt=0;nt<4;++nt)
                acc[mt][nt] = (f32x4){0.f,0.f,0.f,0.f};
        #pragma unroll
        for(int ks=0; ks<4; ++ks){
            bh8 b[4];
            #pragma unroll
            for(int nt=0; nt<4; ++nt)
                b[nt] = ld_frag(W + (size_t)(nhalf + nt*16 + lm)*128 + ks*32 + quad*8);
            #pragma unroll
            for(int mt=0; mt<4; ++mt)
                #pragma unroll
                for(int nt=0; nt<4; ++nt)
                    acc[mt][nt] = MFMA(a[mt][ks], b[nt], acc[mt][nt], 0, 0, 0);
        }
        float bv[4];
        #pragma unroll
        for(int nt=0; nt<4; ++nt) bv[nt] = bf2f(pb[BOFF[iw] + nhalf + nt*16 + lm]);
        #pragma unroll
        for(int mt=0; mt<4; ++mt){
            int mrow = m0 + mhalf + mt*16 + quad*4;
            float mk[4];
            if(iw==2){
                #pragma unroll
                for(int r=0;r<4;++r) mk[r] = (float)mask[mrow+r];
            }
            #pragma unroll
            for(int nt=0; nt<4; ++nt){
                #pragma unroll
                for(int r=0; r<4; ++r){
                    float x = acc[mt][nt][r] + bv[nt];
                    if(iw==3) x = 1.f/(1.f + __expf(-x));
                    if(iw==2) x *= mk[r];
                    st[(mhalf + mt*16 + quad*4 + r)*LDS_P + nhalf + nt*16 + lm] = f2bf(x);
                }
            }
        }
        __syncthreads();
        {
            int row = tid>>1, half = tid&1;
            const u16* src = st + row*LDS_P + half*64;
            u16* dst = outs[iw] + (size_t)(m0 + row)*128 + half*64;
            #pragma unroll
            for(int it=0; it<8; ++it)
                ((int4*)dst)[it] = ((const int4*)src)[it];
        }
        __syncthreads();
    }
}

// ---------------- MFMA o-proj: attn -> out (x mask, dual dtype store) ----------------
__global__ __launch_bounds__(256,2)
void oproj_kernel(const u16* __restrict__ attn, const u16* __restrict__ pb,
                  const int* __restrict__ mask, const u32* __restrict__ flagp,
                  void* __restrict__ out){
    __shared__ u16 st[128*LDS_P];
    int tid = threadIdx.x;
    int lane = tid&63, wv = tid>>6;
    int mhalf = (wv>>1)*64, nhalf = (wv&1)*64;
    int lm = lane&15, quad = lane>>4;
    int m0 = blockIdx.x*128;

    f32x4 acc[4][4];
    #pragma unroll
    for(int mt=0;mt<4;++mt)
        #pragma unroll
        for(int nt=0;nt<4;++nt)
            acc[mt][nt] = (f32x4){0.f,0.f,0.f,0.f};

    const u16* Abase = attn + (size_t)(m0 + mhalf + lm)*128 + quad*8;
    const u16* W = pb + P_OW;
    #pragma unroll
    for(int ks=0; ks<4; ++ks){
        bh8 a[4], b[4];
        #pragma unroll
        for(int mt=0; mt<4; ++mt)
            a[mt] = ld_frag(Abase + (size_t)mt*16*128 + ks*32);
        #pragma unroll
        for(int nt=0; nt<4; ++nt)
            b[nt] = ld_frag(W + (size_t)(nhalf + nt*16 + lm)*128 + ks*32 + quad*8);
        #pragma unroll
        for(int mt=0; mt<4; ++mt)
            #pragma unroll
            for(int nt=0; nt<4; ++nt)
                acc[mt][nt] = MFMA(a[mt], b[nt], acc[mt][nt], 0, 0, 0);
    }
    float bv[4];
    #pragma unroll
    for(int nt=0; nt<4; ++nt) bv[nt] = bf2f(pb[P_OB + nhalf + nt*16 + lm]);
    #pragma unroll
    for(int mt=0; mt<4; ++mt){
        int mrow = m0 + mhalf + mt*16 + quad*4;
        float mk[4];
        #pragma unroll
        for(int r=0;r<4;++r) mk[r] = (float)mask[mrow+r];
        #pragma unroll
        for(int nt=0; nt<4; ++nt)
            #pragma unroll
            for(int r=0; r<4; ++r){
                float x = (acc[mt][nt][r] + bv[nt]) * mk[r];
                st[(mhalf + mt*16 + quad*4 + r)*LDS_P + nhalf + nt*16 + lm] = f2bf(x);
            }
    }
    __syncthreads();
    {
        int row = tid>>1, half = tid&1;
        const u16* src = st + row*LDS_P + half*64;
        bool isbf = (*flagp != 0u);
        if(isbf){
            u16* dst = (u16*)out + (size_t)(m0 + row)*128 + half*64;
            #pragma unroll
            for(int it=0; it<8; ++it)
                ((int4*)dst)[it] = ((const int4*)src)[it];
        } else {
            float* dst = (float*)out + (size_t)(m0 + row)*128 + half*64;
            #pragma unroll
            for(int it=0; it<8; ++it){
                float f[8]; cvt8(((const int4*)src)[it], f);
                float4 lo; lo.x=f[0]; lo.y=f[1]; lo.z=f[2]; lo.w=f[3];
                float4 hi; hi.x=f[4]; hi.y=f[5]; hi.z=f[6]; hi.w=f[7];
                ((float4*)dst)[it*2  ] = lo;
                ((float4*)dst)[it*2+1] = hi;
            }
        }
    }
}

// ---------------- fused feature-maps + kv + attention (MFMA), one block per (row,h) ----------------
// LDS map (bytes):
//   mask_f  [256 f32]          @ 0      .. 1024
//   vT      [48][280] u16      @ 1024   .. 27904   (v^T; row 32 = ones for ksum; 33..47 garbage-ok)
//   kfT     [64][280] u16      @ 27904  .. 63744   (kf^T, [f][n])
//   qf      [256][88] u16      @ 27904  .. 72960   (aliases kfT after kv GEMM)
//   kvT     [48][88]  u16      @ 72960  .. 81408   (kv^T [d][f]; row 32 = ksum)
#define SM_VT   1024
#define SM_KF   27904
#define SM_QF   27904
#define SM_KVT  72960
#define SM_TOT  81408
#define ST_N    280   // u16 stride for n-major rows (bank step 12 -> <=2-way)
#define ST_F    88    // u16 stride for f-major rows (bank step 12)

__global__ __launch_bounds__(256)
void fused_attn_kernel(const u16* __restrict__ k, const u16* __restrict__ v,
                       const u16* __restrict__ q, const u16* __restrict__ gate,
                       const int* __restrict__ mask, const u16* __restrict__ pb,
                       u16* __restrict__ attn){
    __shared__ __align__(16) char smem[SM_TOT];
    float* mask_f = (float*)smem;
    u16* vT  = (u16*)(smem + SM_VT);
    u16* kfT = (u16*)(smem + SM_KF);
    u16* qf  = (u16*)(smem + SM_QF);
    u16* kvT = (u16*)(smem + SM_KVT);

    int g = blockIdx.x, row = g>>2, h = g&3;
    int tid = threadIdx.x;
    int lane = tid & 63, wv = tid >> 6;
    int lm = lane & 15, quad = lane >> 4;
    size_t base = (size_t)row*256*128 + h*32;

    // ---- phase 0: stage v^T (+ones row), mask ----
    {
        int n = tid;
        const int4* vg = (const int4*)(v + base + (size_t)n*128);
        union { int4 i4[4]; u16 u[32]; } vv;
        vv.i4[0]=vg[0]; vv.i4[1]=vg[1]; vv.i4[2]=vg[2]; vv.i4[3]=vg[3];
        mask_f[n] = (float)mask[row*256 + n];
        #pragma unroll
        for(int d=0; d<32; ++d) vT[d*ST_N + n] = vv.u[d];
        if(tid < 64){
            int2 o2; o2.x = (int)0x3F803F80u; o2.y = (int)0x3F803F80u;
            *(int2*)(vT + 32*ST_N + tid*4) = o2;
        }
    }
    __syncthreads();

    // ---- phase 1: kf^T = featmap(k_h) * mask, [f][n] layout ----
    {
        bh8 b0 = ld_frag(pb + P_KFW + lm*32 + quad*8);
        bh8 b1 = ld_frag(pb + P_KFW + (16+lm)*32 + quad*8);
        float bb0 = bf2f(pb[P_KFB + lm]);
        float bb1 = bf2f(pb[P_KFB + 16 + lm]);
        #pragma unroll
        for(int mt=0; mt<4; ++mt){
            bh8 a = ld_frag(k + base + (size_t)(wv*64 + mt*16 + lm)*128 + quad*8);
            f32x4 ac0 = (f32x4){0,0,0,0}, ac1 = (f32x4){0,0,0,0};
            ac0 = MFMA(a, b0, ac0, 0,0,0);
            ac1 = MFMA(a, b1, ac1, 0,0,0);
            #pragma unroll
            for(int r=0;r<4;++r){
                int n = wv*64 + mt*16 + quad*4 + r;
                float mk = mask_f[n];
                float m0 = fminf(8.f, fmaxf(-8.f, ac0[r] + bb0));
                float m1 = fminf(8.f, fmaxf(-8.f, ac1[r] + bb1));
                kfT[(lm   )*ST_N + n] = f2bf(__expf( m0)*mk);
                kfT[(lm+32)*ST_N + n] = f2bf(__expf(-m0)*mk);
                kfT[(lm+16)*ST_N + n] = f2bf(__expf( m1)*mk);
                kfT[(lm+48)*ST_N + n] = f2bf(__expf(-m1)*mk);
            }
        }
    }
    __syncthreads();

    // ---- phase 2: kv^T[d][f] = (kf^T · v)^T, N=33 (col 32 = ksum via ones row) ----
    {
        f32x4 acc[3];
        #pragma unroll
        for(int nt=0;nt<3;++nt) acc[nt] = (f32x4){0,0,0,0};
        #pragma unroll
        for(int ks=0; ks<8; ++ks){
            bh8 a = ld_frag(kfT + (size_t)(wv*16 + lm)*ST_N + ks*32 + quad*8);
            #pragma unroll
            for(int nt=0; nt<3; ++nt){
                bh8 b = ld_frag(vT + (size_t)(nt*16 + lm)*ST_N + ks*32 + quad*8);
                acc[nt] = MFMA(a, b, acc[nt], 0,0,0);
            }
        }
        #pragma unroll
        for(int nt=0; nt<3; ++nt)
            #pragma unroll
            for(int r=0;r<4;++r){
                int f = wv*16 + quad*4 + r;
                if(nt<2)           kvT[(nt*16+lm)*ST_F + f] = f2bf(acc[nt][r]);
                else if(lm==0)     kvT[32*ST_F + f]         = f2bf(acc[2][r]);
            }
    }
    __syncthreads();

    // ---- phase 3: qf[n][f] = featmap(q_h) ----
    {
        bh8 b0 = ld_frag(pb + P_QFW + lm*32 + quad*8);
        bh8 b1 = ld_frag(pb + P_QFW + (16+lm)*32 + quad*8);
        float bb0 = bf2f(pb[P_QFB + lm]);
        float bb1 = bf2f(pb[P_QFB + 16 + lm]);
        #pragma unroll
        for(int mt=0; mt<4; ++mt){
            bh8 a = ld_frag(q + base + (size_t)(wv*64 + mt*16 + lm)*128 + quad*8);
            f32x4 ac0 = (f32x4){0,0,0,0}, ac1 = (f32x4){0,0,0,0};
            ac0 = MFMA(a, b0, ac0, 0,0,0);
            ac1 = MFMA(a, b1, ac1, 0,0,0);
            #pragma unroll
            for(int r=0;r<4;++r){
                int n = wv*64 + mt*16 + quad*4 + r;
                float m0 = fminf(8.f, fmaxf(-8.f, ac0[r] + bb0));
                float m1 = fminf(8.f, fmaxf(-8.f, ac1[r] + bb1));
                qf[n*ST_F + lm     ] = f2bf(__expf( m0));
                qf[n*ST_F + lm + 32] = f2bf(__expf(-m0));
                qf[n*ST_F + lm + 16] = f2bf(__expf( m1));
                qf[n*ST_F + lm + 48] = f2bf(__expf(-m1));
            }
        }
    }
    __syncthreads();

    // ---- phase 4: out[n][d] = (qf·kv)/den * gate;  den from n-tile 2 col 32 ----
    {
        f32x4 acc[4][3];
        #pragma unroll
        for(int mt=0;mt<4;++mt)
            #pragma unroll
            for(int nt=0;nt<3;++nt) acc[mt][nt] = (f32x4){0,0,0,0};
        #pragma unroll
        for(int ks=0; ks<2; ++ks){
            bh8 b[3];
            #pragma unroll
            for(int nt=0; nt<3; ++nt)
                b[nt] = ld_frag(kvT + (size_t)(nt*16 + lm)*ST_F + ks*32 + quad*8);
            #pragma unroll
            for(int mt=0; mt<4; ++mt){
                bh8 a = ld_frag(qf + (size_t)(wv*64 + mt*16 + lm)*ST_F + ks*32 + quad*8);
                #pragma unroll
                for(int nt=0; nt<3; ++nt)
                    acc[mt][nt] = MFMA(a, b[nt], acc[mt][nt], 0,0,0);
            }
        }
        #pragma unroll
        for(int mt=0; mt<4; ++mt)
            #pragma unroll
            for(int r=0; r<4; ++r){
                int n = wv*64 + mt*16 + quad*4 + r;
                size_t t = (size_t)row*256 + n;
                float den = __shfl(acc[mt][2][r], lane & 48, 64);
                float rcp = 1.f / fmaxf(den, 1e-6f);
                const u16* gp = gate + t*128 + h*32;
                u16* op = attn + t*128 + h*32;
                float o0 = acc[mt][0][r] * rcp * bf2f(gp[lm]);
                float o1 = acc[mt][1][r] * rcp * bf2f(gp[16+lm]);
                op[lm]    = f2bf(o0);
                op[16+lm] = f2bf(o1);
            }
    }
}

// ---------------- launch ----------------
extern "C" void kernel_launch(void* const* d_in, const int* in_sizes, int n_in,
                              void* d_out, int out_size, void* d_ws, size_t ws_size,
                              hipStream_t stream){
    const void* z    = d_in[0];
    const int*  mask = (const int*)d_in[1];

    char* ws = (char*)d_ws;
    const size_t MB = (size_t)1<<20;
    u16*   zn   = (u16*)(ws + 0*MB);      // 16 MB  [t][128] bf16
    u16*   q    = (u16*)(ws + 16*MB);     // 16 MB  q-proj; later reused as attn
    u16*   k    = (u16*)(ws + 32*MB);     // 16 MB
    u16*   v    = (u16*)(ws + 48*MB);     // 16 MB  (masked)
    u16*   gate = (u16*)(ws + 64*MB);     // 16 MB  (sigmoid applied)
    u16*   pb   = (u16*)(ws + 88*MB + 512*1024);  // ~166 KB bf16 param block
    u32*   flag = (u32*)(ws + 89*MB);     // 4 B dtype flag
    u16*   attn = q;                      // alias (safe: fused kernel reads its q slice before writing)

    detect_kernel<<<1,256,0,stream>>>((const u32*)z, flag);
    convert_params<<<(P_TOT+255)/256,256,0,stream>>>(
        d_in[2], d_in[3], d_in[4], d_in[5], d_in[6], d_in[7], d_in[8], d_in[9],
        d_in[10], d_in[11], d_in[12], d_in[13], d_in[14], d_in[15], d_in[16], d_in[17],
        flag, pb);
    ln_kernel<<<16384,256,0,stream>>>(z, pb, flag, zn);
    proj4_kernel<<<512,256,0,stream>>>(zn, pb, mask, q, k, v, gate);
    fused_attn_kernel<<<1024,256,0,stream>>>(k, v, q, gate, mask, pb, attn);
    oproj_kernel<<<512,256,0,stream>>>(attn, pb, mask, flag, d_out);
}

// Round 5
// 188.937 us; speedup vs baseline: 1.9400x; 1.1511x over previous
//
#include <hip/hip_runtime.h>
#include <stdint.h>

#define DEV __device__ __forceinline__

typedef unsigned short u16;
typedef unsigned int u32;
typedef short bh8 __attribute__((ext_vector_type(8)));
typedef float f32x4 __attribute__((ext_vector_type(4)));

// ---------- bf16 helpers ----------
DEV float bf2f(u16 v){ return __uint_as_float(((u32)v)<<16); }
DEV u16 f2bf(float f){
    u32 x = __float_as_uint(f);
    x += 0x7fffu + ((x>>16)&1u);
    return (u16)(x>>16);
}
DEV void cvt8(int4 r, float* f){
    u32 a=(u32)r.x, b=(u32)r.y, c=(u32)r.z, d=(u32)r.w;
    f[0]=__uint_as_float(a<<16); f[1]=__uint_as_float(a&0xffff0000u);
    f[2]=__uint_as_float(b<<16); f[3]=__uint_as_float(b&0xffff0000u);
    f[4]=__uint_as_float(c<<16); f[5]=__uint_as_float(c&0xffff0000u);
    f[6]=__uint_as_float(d<<16); f[7]=__uint_as_float(d&0xffff0000u);
}
DEV bh8 ld_frag(const u16* p){
    int4 v = *(const int4*)p;
    union{ int4 i; bh8 h; } u; u.i = v; return u.h;
}
#define MFMA __builtin_amdgcn_mfma_f32_16x16x32_bf16

// Problem constants: BSZ=1, S=256, C=128, H=4, D=32, F=64.
// tokens T=65536 (row=t>>8, n=t&255)

// Param block layout (elements, bf16) inside workspace:
#define P_LNW 0
#define P_LNB 128
#define P_QW  256
#define P_QB  16640
#define P_KW  16768
#define P_KB  33152
#define P_VW  33280
#define P_VB  49664
#define P_QFW 49792
#define P_QFB 50816
#define P_KFW 50848
#define P_KFB 51872
#define P_GW  51904
#define P_GB  68288
#define P_OW  68416
#define P_OB  84800
#define P_TOT 84928
// combined feature-map weights (appended, written by prep_combine):
#define P_CQW 84928    // [h][j][c] 4*32*128
#define P_CQB 101312   // [h][j]    4*32
#define P_CKW 101440
#define P_CKB 117824
#define P_XTOT 117952

// ---------------- dtype detect: flag=1 if inputs are bf16, 0 if f32 ----------------
__global__ void detect_kernel(const u32* __restrict__ z, u32* __restrict__ flag){
    int tid = threadIdx.x;
    u32 w = z[(size_t)tid*997];
    u32 b0 = w & 0xFFFFu;
    int e = (int)((b0>>7)&0xFF);
    int good = (e>=96 && e<=150) ? 1 : 0;
    __shared__ int red[4];
    #pragma unroll
    for(int o=1;o<64;o<<=1) good += __shfl_xor(good,o,64);
    if((tid&63)==0) red[tid>>6]=good;
    __syncthreads();
    if(tid==0) *flag = ((red[0]+red[1]+red[2]+red[3]) > 192) ? 1u : 0u;
}

// ---------------- convert all params to bf16 param block ----------------
__global__ void convert_params(
    const void* p0, const void* p1, const void* p2, const void* p3,
    const void* p4, const void* p5, const void* p6, const void* p7,
    const void* p8, const void* p9, const void* p10, const void* p11,
    const void* p12, const void* p13, const void* p14, const void* p15,
    const u32* __restrict__ flag, u16* __restrict__ dst){
    int idx = blockIdx.x*256 + threadIdx.x;
    if(idx >= P_TOT) return;
    const int offs[17] = {P_LNW,P_LNB,P_QW,P_QB,P_KW,P_KB,P_VW,P_VB,
                          P_QFW,P_QFB,P_KFW,P_KFB,P_GW,P_GB,P_OW,P_OB,P_TOT};
    const void* ptrs[16] = {p0,p1,p2,p3,p4,p5,p6,p7,p8,p9,p10,p11,p12,p13,p14,p15};
    int tsel = 0;
    #pragma unroll
    for(int i=1;i<16;++i) if(idx >= offs[i]) tsel = i;
    int local = idx - offs[tsel];
    u16 v;
    if(*flag) v = ((const u16*)ptrs[tsel])[local];
    else      v = f2bf(((const float*)ptrs[tsel])[local]);
    dst[idx] = v;
}

// ---------------- prep: fold feature-map weights into q/k projections ----------------
// Wc[h][j][c] = sum_d F[j][d] * W[h*32+d][c];  bc[h][j] = sum_d F[j][d]*b[h*32+d] + fb[j]
__global__ void prep_combine(u16* __restrict__ pb){
    if(blockIdx.x < 128){
        int idx = blockIdx.x*256 + threadIdx.x;     // [0, 32768)
        int sel = idx >> 14;                        // 0=q, 1=k
        int rem = idx & 16383;
        int h = rem >> 12, j = (rem >> 7) & 31, c = rem & 127;
        int FW = sel ? P_KFW : P_QFW;
        int W  = sel ? P_KW  : P_QW;
        float s = 0.f;
        #pragma unroll
        for(int d=0; d<32; ++d)
            s += bf2f(pb[FW + j*32 + d]) * bf2f(pb[W + (h*32+d)*128 + c]);
        pb[(sel ? P_CKW : P_CQW) + h*4096 + j*128 + c] = f2bf(s);
    } else {
        int t = threadIdx.x;                        // 256 bias entries
        int sel = t >> 7, h = (t >> 5) & 3, j = t & 31;
        int FW = sel ? P_KFW : P_QFW;
        int FB = sel ? P_KFB : P_QFB;
        int B  = sel ? P_KB  : P_QB;
        float s = bf2f(pb[FB + j]);
        #pragma unroll
        for(int d=0; d<32; ++d)
            s += bf2f(pb[FW + j*32 + d]) * bf2f(pb[B + h*32 + d]);
        pb[(sel ? P_CKB : P_CQB) + h*32 + j] = f2bf(s);
    }
}

// ---------------- LayerNorm: one wave per token ----------------
__global__ void ln_kernel(const void* __restrict__ zv, const u16* __restrict__ pb,
                          const u32* __restrict__ flag, u16* __restrict__ zn){
    int t = blockIdx.x*4 + (threadIdx.x>>6);
    int lane = threadIdx.x & 63;
    float x0, x1;
    if(*flag){
        u32 pr = ((const u32*)zv)[(size_t)t*64 + lane];
        x0 = __uint_as_float(pr<<16); x1 = __uint_as_float(pr & 0xffff0000u);
    } else {
        float2 v = ((const float2*)zv)[(size_t)t*64 + lane];
        x0 = v.x; x1 = v.y;
    }
    float s = x0 + x1, s2 = x0*x0 + x1*x1;
    #pragma unroll
    for(int o=1;o<64;o<<=1){ s += __shfl_xor(s,o,64); s2 += __shfl_xor(s2,o,64); }
    float mean = s*(1.f/128.f);
    float var  = s2*(1.f/128.f) - mean*mean;
    float rs = rsqrtf(var + 1e-5f);
    int c0 = 2*lane;
    float w0 = bf2f(pb[P_LNW+c0]), w1 = bf2f(pb[P_LNW+c0+1]);
    float b0 = bf2f(pb[P_LNB+c0]), b1 = bf2f(pb[P_LNB+c0+1]);
    float o0 = (x0-mean)*rs*w0 + b0;
    float o1 = (x1-mean)*rs*w1 + b1;
    u32 po = (u32)f2bf(o0) | ((u32)f2bf(o1)<<16);
    *(u32*)(zn + (size_t)t*128 + c0) = po;
}

// ---------------- mega kernel: one block per row; all heads, proj->featmap->kv->attn ----------------
// LDS (bytes):
//   mask_f [256 f32]      @ 0       (1024)
//   kfT    [64][264] u16  @ 1024    (33792)  kf^T [feature][n], masked
//   vT     [33][264] u16  @ 34816   (17424)  v^T [d][n] masked; row 32 = ones (persistent)
//   qf     [256][68] u16  @ 1024    (34816)  aliases kfT (+vT rows 0-1); [n][feature]
//   kvT    [33][68]  u16  @ 52240   (4488)   kv^T [d][f]; row 32 = ksum
#define ST_N 264
#define ST_F 68
#define SM_KF   1024
#define SM_VT   34816
#define SM_QF   1024
#define SM_KVT  52240
#define SM_TOT  56736

__global__ __launch_bounds__(256,1)
void mega_kernel(const u16* __restrict__ zn, const int* __restrict__ mask,
                 const u16* __restrict__ pb, u16* __restrict__ attn){
    __shared__ __align__(16) char smem[SM_TOT];
    float* mask_f = (float*)smem;
    u16* kfT = (u16*)(smem + SM_KF);
    u16* vT  = (u16*)(smem + SM_VT);
    u16* qf  = (u16*)(smem + SM_QF);
    u16* kvT = (u16*)(smem + SM_KVT);

    int row = blockIdx.x;
    int tid = threadIdx.x, lane = tid & 63, wv = tid >> 6;
    int lm = lane & 15, quad = lane >> 4;

    mask_f[tid] = (float)mask[row*256 + tid];
    if(tid < 64){
        int2 ones; ones.x = 0x3F803F80; ones.y = 0x3F803F80;
        *(int2*)(vT + 32*ST_N + tid*4) = ones;     // ksum ones-row, persistent
    }

    // zn A-frags: loaded once, reused by all 16 GEMMs (4 weights x 4 heads)
    bh8 a[4][4];
    {
        const u16* Ab = zn + ((size_t)row*256 + wv*64 + lm)*128 + quad*8;
        #pragma unroll
        for(int mt=0; mt<4; ++mt)
            #pragma unroll
            for(int ks=0; ks<4; ++ks)
                a[mt][ks] = ld_frag(Ab + (size_t)mt*16*128 + ks*32);
    }
    bh8 onesf;
    { union{int4 i; bh8 h;} u; u.i.x=u.i.y=u.i.z=u.i.w=0x3F803F80; onesf = u.h; }

    __syncthreads();

    for(int h=0; h<4; ++h){
        f32x4 gacc[4][2];
        // ---- phase 1a: m_k = zn·Wc_k^T + bc_k -> clip/exp -> kfT (masked) ----
        {
            f32x4 acc[4][2];
            #pragma unroll
            for(int mt=0;mt<4;++mt){ acc[mt][0]=(f32x4){0,0,0,0}; acc[mt][1]=(f32x4){0,0,0,0}; }
            #pragma unroll
            for(int ks=0; ks<4; ++ks){
                bh8 b0 = ld_frag(pb + P_CKW + h*4096 + lm*128      + ks*32 + quad*8);
                bh8 b1 = ld_frag(pb + P_CKW + h*4096 + (16+lm)*128 + ks*32 + quad*8);
                #pragma unroll
                for(int mt=0; mt<4; ++mt){
                    acc[mt][0] = MFMA(a[mt][ks], b0, acc[mt][0], 0,0,0);
                    acc[mt][1] = MFMA(a[mt][ks], b1, acc[mt][1], 0,0,0);
                }
            }
            float bb0 = bf2f(pb[P_CKB + h*32 + lm]);
            float bb1 = bf2f(pb[P_CKB + h*32 + 16 + lm]);
            #pragma unroll
            for(int mt=0; mt<4; ++mt)
                #pragma unroll
                for(int r=0; r<4; ++r){
                    int n = wv*64 + mt*16 + quad*4 + r;
                    float mk = mask_f[n];
                    float m0 = fminf(8.f, fmaxf(-8.f, acc[mt][0][r] + bb0));
                    float m1 = fminf(8.f, fmaxf(-8.f, acc[mt][1][r] + bb1));
                    kfT[(lm   )*ST_N + n] = f2bf(__expf( m0)*mk);
                    kfT[(lm+32)*ST_N + n] = f2bf(__expf(-m0)*mk);
                    kfT[(lm+16)*ST_N + n] = f2bf(__expf( m1)*mk);
                    kfT[(lm+48)*ST_N + n] = f2bf(__expf(-m1)*mk);
                }
        }
        // ---- phase 1b: v = (zn·Wv_h^T + vb)*mask -> vT ----
        {
            f32x4 acc[4][2];
            #pragma unroll
            for(int mt=0;mt<4;++mt){ acc[mt][0]=(f32x4){0,0,0,0}; acc[mt][1]=(f32x4){0,0,0,0}; }
            #pragma unroll
            for(int ks=0; ks<4; ++ks){
                bh8 b0 = ld_frag(pb + P_VW + (size_t)(h*32 + lm)*128      + ks*32 + quad*8);
                bh8 b1 = ld_frag(pb + P_VW + (size_t)(h*32 + 16 + lm)*128 + ks*32 + quad*8);
                #pragma unroll
                for(int mt=0; mt<4; ++mt){
                    acc[mt][0] = MFMA(a[mt][ks], b0, acc[mt][0], 0,0,0);
                    acc[mt][1] = MFMA(a[mt][ks], b1, acc[mt][1], 0,0,0);
                }
            }
            float bb0 = bf2f(pb[P_VB + h*32 + lm]);
            float bb1 = bf2f(pb[P_VB + h*32 + 16 + lm]);
            #pragma unroll
            for(int mt=0; mt<4; ++mt)
                #pragma unroll
                for(int r=0; r<4; ++r){
                    int n = wv*64 + mt*16 + quad*4 + r;
                    float mk = mask_f[n];
                    vT[(lm   )*ST_N + n] = f2bf((acc[mt][0][r] + bb0)*mk);
                    vT[(16+lm)*ST_N + n] = f2bf((acc[mt][1][r] + bb1)*mk);
                }
        }
        // ---- phase 1c: gate = sigmoid(zn·Wg_h^T + gb) -> registers (C/D layout matches attn) ----
        {
            f32x4 acc[4][2];
            #pragma unroll
            for(int mt=0;mt<4;++mt){ acc[mt][0]=(f32x4){0,0,0,0}; acc[mt][1]=(f32x4){0,0,0,0}; }
            #pragma unroll
            for(int ks=0; ks<4; ++ks){
                bh8 b0 = ld_frag(pb + P_GW + (size_t)(h*32 + lm)*128      + ks*32 + quad*8);
                bh8 b1 = ld_frag(pb + P_GW + (size_t)(h*32 + 16 + lm)*128 + ks*32 + quad*8);
                #pragma unroll
                for(int mt=0; mt<4; ++mt){
                    acc[mt][0] = MFMA(a[mt][ks], b0, acc[mt][0], 0,0,0);
                    acc[mt][1] = MFMA(a[mt][ks], b1, acc[mt][1], 0,0,0);
                }
            }
            float bb0 = bf2f(pb[P_GB + h*32 + lm]);
            float bb1 = bf2f(pb[P_GB + h*32 + 16 + lm]);
            #pragma unroll
            for(int mt=0; mt<4; ++mt)
                #pragma unroll
                for(int r=0; r<4; ++r){
                    gacc[mt][0][r] = 1.f/(1.f + __expf(-(acc[mt][0][r] + bb0)));
                    gacc[mt][1][r] = 1.f/(1.f + __expf(-(acc[mt][1][r] + bb1)));
                }
        }
        __syncthreads();
        // ---- phase 2: kvT[d][f] = sum_n kfT[f][n]*vT[d][n]; ksum via ones-frag ----
        {
            f32x4 acc0=(f32x4){0,0,0,0}, acc1=(f32x4){0,0,0,0}, acc2=(f32x4){0,0,0,0};
            #pragma unroll
            for(int ks=0; ks<8; ++ks){
                bh8 aa = ld_frag(kfT + (size_t)(wv*16+lm)*ST_N + ks*32 + quad*8);
                bh8 b0 = ld_frag(vT + (size_t)lm*ST_N      + ks*32 + quad*8);
                bh8 b1 = ld_frag(vT + (size_t)(16+lm)*ST_N + ks*32 + quad*8);
                acc0 = MFMA(aa, b0, acc0, 0,0,0);
                acc1 = MFMA(aa, b1, acc1, 0,0,0);
                acc2 = MFMA(aa, onesf, acc2, 0,0,0);
            }
            #pragma unroll
            for(int r=0; r<4; ++r){
                int f = wv*16 + quad*4 + r;
                kvT[(lm   )*ST_F + f] = f2bf(acc0[r]);
                kvT[(16+lm)*ST_F + f] = f2bf(acc1[r]);
                if(lm==0) kvT[32*ST_F + f] = f2bf(acc2[r]);
            }
        }
        __syncthreads();
        // ---- phase 3: m_q = zn·Wc_q^T + bc_q -> clip/exp -> qf [n][f] (aliases kfT/vT) ----
        {
            f32x4 acc[4][2];
            #pragma unroll
            for(int mt=0;mt<4;++mt){ acc[mt][0]=(f32x4){0,0,0,0}; acc[mt][1]=(f32x4){0,0,0,0}; }
            #pragma unroll
            for(int ks=0; ks<4; ++ks){
                bh8 b0 = ld_frag(pb + P_CQW + h*4096 + lm*128      + ks*32 + quad*8);
                bh8 b1 = ld_frag(pb + P_CQW + h*4096 + (16+lm)*128 + ks*32 + quad*8);
                #pragma unroll
                for(int mt=0; mt<4; ++mt){
                    acc[mt][0] = MFMA(a[mt][ks], b0, acc[mt][0], 0,0,0);
                    acc[mt][1] = MFMA(a[mt][ks], b1, acc[mt][1], 0,0,0);
                }
            }
            float bb0 = bf2f(pb[P_CQB + h*32 + lm]);
            float bb1 = bf2f(pb[P_CQB + h*32 + 16 + lm]);
            #pragma unroll
            for(int mt=0; mt<4; ++mt)
                #pragma unroll
                for(int r=0; r<4; ++r){
                    int n = wv*64 + mt*16 + quad*4 + r;
                    float m0 = fminf(8.f, fmaxf(-8.f, acc[mt][0][r] + bb0));
                    float m1 = fminf(8.f, fmaxf(-8.f, acc[mt][1][r] + bb1));
                    qf[n*ST_F + lm     ] = f2bf(__expf( m0));
                    qf[n*ST_F + lm + 32] = f2bf(__expf(-m0));
                    qf[n*ST_F + lm + 16] = f2bf(__expf( m1));
                    qf[n*ST_F + lm + 48] = f2bf(__expf(-m1));
                }
        }
        __syncthreads();
        // ---- phase 4: out = (qf·kvT^T)/den * gate; den col via kvT ksum row (all lanes) ----
        {
            f32x4 acc[4][3];
            #pragma unroll
            for(int mt=0;mt<4;++mt)
                #pragma unroll
                for(int nt=0;nt<3;++nt) acc[mt][nt]=(f32x4){0,0,0,0};
            #pragma unroll
            for(int ks=0; ks<2; ++ks){
                bh8 b0 = ld_frag(kvT + (size_t)lm*ST_F      + ks*32 + quad*8);
                bh8 b1 = ld_frag(kvT + (size_t)(16+lm)*ST_F + ks*32 + quad*8);
                bh8 b2 = ld_frag(kvT + (size_t)32*ST_F      + ks*32 + quad*8); // ksum, broadcast
                #pragma unroll
                for(int mt=0; mt<4; ++mt){
                    bh8 aa = ld_frag(qf + (size_t)(wv*64+mt*16+lm)*ST_F + ks*32 + quad*8);
                    acc[mt][0] = MFMA(aa, b0, acc[mt][0], 0,0,0);
                    acc[mt][1] = MFMA(aa, b1, acc[mt][1], 0,0,0);
                    acc[mt][2] = MFMA(aa, b2, acc[mt][2], 0,0,0);
                }
            }
            #pragma unroll
            for(int mt=0; mt<4; ++mt)
                #pragma unroll
                for(int r=0; r<4; ++r){
                    int n = wv*64 + mt*16 + quad*4 + r;
                    float den = acc[mt][2][r];            // every col of tile 2 = qf·ksum
                    float rcp = 1.f / fmaxf(den, 1e-6f);
                    u16* op = attn + ((size_t)row*256 + n)*128 + h*32;
                    op[lm]      = f2bf(acc[mt][0][r]*rcp*gacc[mt][0][r]);
                    op[16+lm]   = f2bf(acc[mt][1][r]*rcp*gacc[mt][1][r]);
                }
        }
        __syncthreads();   // next head's kfT/vT writes alias qf
    }
}

// ---------------- MFMA o-proj: attn -> out (x mask, dual dtype store) ----------------
#define LDS_P 136
__global__ __launch_bounds__(256,2)
void oproj_kernel(const u16* __restrict__ attn, const u16* __restrict__ pb,
                  const int* __restrict__ mask, const u32* __restrict__ flagp,
                  void* __restrict__ out){
    __shared__ u16 st[128*LDS_P];
    int tid = threadIdx.x;
    int lane = tid&63, wv = tid>>6;
    int mhalf = (wv>>1)*64, nhalf = (wv&1)*64;
    int lm = lane&15, quad = lane>>4;
    int m0 = blockIdx.x*128;

    f32x4 acc[4][4];
    #pragma unroll
    for(int mt=0;mt<4;++mt)
        #pragma unroll
        for(int nt=0;nt<4;++nt)
            acc[mt][nt] = (f32x4){0.f,0.f,0.f,0.f};

    const u16* Abase = attn + (size_t)(m0 + mhalf + lm)*128 + quad*8;
    const u16* W = pb + P_OW;
    #pragma unroll
    for(int ks=0; ks<4; ++ks){
        bh8 a[4], b[4];
        #pragma unroll
        for(int mt=0; mt<4; ++mt)
            a[mt] = ld_frag(Abase + (size_t)mt*16*128 + ks*32);
        #pragma unroll
        for(int nt=0; nt<4; ++nt)
            b[nt] = ld_frag(W + (size_t)(nhalf + nt*16 + lm)*128 + ks*32 + quad*8);
        #pragma unroll
        for(int mt=0; mt<4; ++mt)
            #pragma unroll
            for(int nt=0; nt<4; ++nt)
                acc[mt][nt] = MFMA(a[mt], b[nt], acc[mt][nt], 0, 0, 0);
    }
    float bv[4];
    #pragma unroll
    for(int nt=0; nt<4; ++nt) bv[nt] = bf2f(pb[P_OB + nhalf + nt*16 + lm]);
    #pragma unroll
    for(int mt=0; mt<4; ++mt){
        int mrow = m0 + mhalf + mt*16 + quad*4;
        float mk[4];
        #pragma unroll
        for(int r=0;r<4;++r) mk[r] = (float)mask[mrow+r];
        #pragma unroll
        for(int nt=0; nt<4; ++nt)
            #pragma unroll
            for(int r=0; r<4; ++r){
                float x = (acc[mt][nt][r] + bv[nt]) * mk[r];
                st[(mhalf + mt*16 + quad*4 + r)*LDS_P + nhalf + nt*16 + lm] = f2bf(x);
            }
    }
    __syncthreads();
    {
        int row = tid>>1, half = tid&1;
        const u16* src = st + row*LDS_P + half*64;
        bool isbf = (*flagp != 0u);
        if(isbf){
            u16* dst = (u16*)out + (size_t)(m0 + row)*128 + half*64;
            #pragma unroll
            for(int it=0; it<8; ++it)
                ((int4*)dst)[it] = ((const int4*)src)[it];
        } else {
            float* dst = (float*)out + (size_t)(m0 + row)*128 + half*64;
            #pragma unroll
            for(int it=0; it<8; ++it){
                float f[8]; cvt8(((const int4*)src)[it], f);
                float4 lo; lo.x=f[0]; lo.y=f[1]; lo.z=f[2]; lo.w=f[3];
                float4 hi; hi.x=f[4]; hi.y=f[5]; hi.z=f[6]; hi.w=f[7];
                ((float4*)dst)[it*2  ] = lo;
                ((float4*)dst)[it*2+1] = hi;
            }
        }
    }
}

// ---------------- launch ----------------
extern "C" void kernel_launch(void* const* d_in, const int* in_sizes, int n_in,
                              void* d_out, int out_size, void* d_ws, size_t ws_size,
                              hipStream_t stream){
    const void* z    = d_in[0];
    const int*  mask = (const int*)d_in[1];

    char* ws = (char*)d_ws;
    const size_t MB = (size_t)1<<20;
    u16*   zn   = (u16*)(ws + 0*MB);      // 16 MB  [t][128] bf16
    u16*   attn = (u16*)(ws + 16*MB);     // 16 MB  [t][128] bf16
    u16*   pb   = (u16*)(ws + 32*MB);     // ~231 KB bf16 param block (incl. combined weights)
    u32*   flag = (u32*)(ws + 33*MB);     // 4 B dtype flag

    detect_kernel<<<1,256,0,stream>>>((const u32*)z, flag);
    convert_params<<<(P_TOT+255)/256,256,0,stream>>>(
        d_in[2], d_in[3], d_in[4], d_in[5], d_in[6], d_in[7], d_in[8], d_in[9],
        d_in[10], d_in[11], d_in[12], d_in[13], d_in[14], d_in[15], d_in[16], d_in[17],
        flag, pb);
    prep_combine<<<129,256,0,stream>>>(pb);
    ln_kernel<<<16384,256,0,stream>>>(z, pb, flag, zn);
    mega_kernel<<<256,256,0,stream>>>(zn, mask, pb, attn);
    oproj_kernel<<<512,256,0,stream>>>(attn, pb, mask, flag, d_out);
}